// Round 11
// baseline (377.260 us; speedup 1.0000x reference)
//
#include <hip/hip_runtime.h>

// Problem constants: B=2, S=2048, D=2048, H=16, KVH=4, HD=128, KVD=512
// qkv row layout: [0,2048) = Q (16 heads x 128), [2048,2560) = K (4 x 128), [2560,3072) = V

typedef __bf16 bf16x8 __attribute__((ext_vector_type(8)));
typedef float  f32x4  __attribute__((ext_vector_type(4)));
typedef float  f32x16 __attribute__((ext_vector_type(16)));

#define LOG2E 1.4426950408889634f
// fixed softmax shift: |score| <= sqrt(128) ~= 11.32 (rms-normed q,k, gain=1)
#define FIXC  16.59099297022308f   // 11.5 * LOG2E

__device__ __forceinline__ float b2f(ushort h) {
  return __builtin_bit_cast(float, ((unsigned)h) << 16);
}
__device__ __forceinline__ ushort f2b(float f) {
  unsigned u = __builtin_bit_cast(unsigned, f);
  return (ushort)((u + 0x7fffu + ((u >> 16) & 1u)) >> 16);
}
__device__ __forceinline__ void async16(ushort* lds, const ushort* g) {
  __builtin_amdgcn_global_load_lds(
      (const __attribute__((address_space(1))) unsigned int*)(const void*)g,
      (__attribute__((address_space(3))) unsigned int*)(void*)lds, 16, 0, 0);
}
__device__ __forceinline__ f32x4 mfma16(bf16x8 a, bf16x8 b, f32x4 c) {
  return __builtin_amdgcn_mfma_f32_16x16x32_bf16(a, b, c, 0, 0, 0);
}
__device__ __forceinline__ f32x16 mfma32(bf16x8 a, bf16x8 b, f32x16 c) {
  return __builtin_amdgcn_mfma_f32_32x32x16_bf16(a, b, c, 0, 0, 0);
}

// ---------------- f32 -> bf16 cast (vectorized) ----------------
__global__ __launch_bounds__(256) void castk(const float* __restrict__ in,
                                             ushort* __restrict__ out) {
  int i = blockIdx.x * 256 + threadIdx.x;
  float4 v = ((const float4*)in)[i];
  ushort4 o = make_ushort4(f2b(v.x), f2b(v.y), f2b(v.z), f2b(v.w));
  ((ushort4*)out)[i] = o;
}

// ---------------- RoPE tables: cos/sin[s][i], i=0..63 ----------------
__global__ void rope_tables(float* __restrict__ cosT, float* __restrict__ sinT) {
  int s = blockIdx.x;
  int i = threadIdx.x;
  float invf = exp2f(-(float)i * (13.287712379549449f / 64.0f));
  float ang = (float)s * invf;
  float sn, cs;
  sincosf(ang, &sn, &cs);
  cosT[s * 64 + i] = cs;
  sinT[s * 64 + i] = sn;
}

// ---------------- GEMM: C[M,N] = A[M,K] * B[N,K]^T (bf16 in, TOUT out) -----
// BK=64, XOR-swizzled LDS (pre-swizzled global source), XCD swizzle. (round-8 state)
__device__ __forceinline__ void store_c(float* C, size_t idx, float v) { C[idx] = v; }
__device__ __forceinline__ void store_c(ushort* C, size_t idx, float v) { C[idx] = f2b(v); }

template <typename TOUT>
__global__ __launch_bounds__(256) void gemm_bt(const ushort* __restrict__ A,
                                               const ushort* __restrict__ Bw,
                                               TOUT* __restrict__ C,
                                               int M, int N, int K) {
  __shared__ __align__(16) ushort As[128 * 64];
  __shared__ __align__(16) ushort Bs[128 * 64];
  int tid = threadIdx.x;
  int lane = tid & 63, wid = tid >> 6;
  int gx = gridDim.x;
  int nwg = gx * gridDim.y;
  int lid = blockIdx.y * gx + blockIdx.x;
  int cpx = nwg >> 3;
  int swz = (lid & 7) * cpx + (lid >> 3);
  int bm = swz / gx, bn = swz % gx;
  int wr = wid >> 1, wc = wid & 1;
  int lr = lane & 15, kg = lane >> 4;
  f32x4 z = {0.f, 0.f, 0.f, 0.f};
  f32x4 acc[4][4];
#pragma unroll
  for (int m = 0; m < 4; ++m)
#pragma unroll
    for (int n = 0; n < 4; ++n) acc[m][n] = z;

  const ushort* Ab = A + (size_t)bm * 128 * K;
  const ushort* Bb = Bw + (size_t)bn * 128 * K;

  for (int k0 = 0; k0 < K; k0 += 64) {
#pragma unroll
    for (int p = 0; p < 4; ++p) {
      int c = p * 256 + tid;
      int r = c >> 3, ch = c & 7;
      int chs = ch ^ (r & 7);
      async16(&As[c * 8], Ab + (size_t)r * K + k0 + chs * 8);
      async16(&Bs[c * 8], Bb + (size_t)r * K + k0 + chs * 8);
    }
    __syncthreads();
    bf16x8 af[4][2], bfr[4][2];
#pragma unroll
    for (int m = 0; m < 4; ++m)
#pragma unroll
      for (int kk = 0; kk < 2; ++kk) {
        int r = wr * 64 + m * 16 + lr;
        int a = (kk * 4 + kg) ^ (r & 7);
        af[m][kk] = *(const bf16x8*)&As[r * 64 + a * 8];
      }
#pragma unroll
    for (int n = 0; n < 4; ++n)
#pragma unroll
      for (int kk = 0; kk < 2; ++kk) {
        int r = wc * 64 + n * 16 + lr;
        int a = (kk * 4 + kg) ^ (r & 7);
        bfr[n][kk] = *(const bf16x8*)&Bs[r * 64 + a * 8];
      }
#pragma unroll
    for (int m = 0; m < 4; ++m)
#pragma unroll
      for (int n = 0; n < 4; ++n)
#pragma unroll
        for (int kk = 0; kk < 2; ++kk)
          acc[m][n] = mfma16(af[m][kk], bfr[n][kk], acc[m][n]);
    __syncthreads();
  }
#pragma unroll
  for (int m = 0; m < 4; ++m)
#pragma unroll
    for (int n = 0; n < 4; ++n)
#pragma unroll
      for (int r4 = 0; r4 < 4; ++r4) {
        int row = bm * 128 + wr * 64 + m * 16 + kg * 4 + r4;
        int col = bn * 128 + wc * 64 + n * 16 + lr;
        store_c(C, (size_t)row * N + col, acc[m][n][r4]);
      }
}

// ---------------- RMS-norm + RoPE (+gain*scale for Q), in place ----------
__global__ __launch_bounds__(256) void rms_rope(ushort* __restrict__ qkv,
                                                const float* __restrict__ gain,
                                                const float* __restrict__ cosT,
                                                const float* __restrict__ sinT) {
  int w = blockIdx.x * 4 + (threadIdx.x >> 6);
  int lane = threadIdx.x & 63;
  int token = w / 20, slot = w % 20;
  int s = token & 2047;
  ushort* p = qkv + (size_t)token * 3072 +
              (slot < 16 ? slot * 128 : 2048 + (slot - 16) * 128);
  float t1 = b2f(p[lane]);
  float t2 = b2f(p[lane + 64]);
  float ss = t1 * t1 + t2 * t2;
#pragma unroll
  for (int off = 32; off >= 1; off >>= 1) ss += __shfl_xor(ss, off);
  float r = rsqrtf(ss * (1.0f / 128.0f) + 1e-6f);
  t1 *= r; t2 *= r;
  float c = cosT[s * 64 + lane], sn = sinT[s * 64 + lane];
  float o1 = t1 * c + t2 * sn;
  float o2 = t2 * c - t1 * sn;
  if (slot < 16) {
    float g = gain[slot] * 0.08838834764831845f;  // q_gain * 1/sqrt(128)
    o1 *= g; o2 *= g;
  }
  p[lane] = f2b(o1);
  p[lane + 64] = f2b(o2);
}

// ---------------- causal GQA flash attention (32x32 mfma, swapped QK) -----
// grid: (16 pairs, B*H=32); block 256 = 4 waves x 32 q-rows. KV tile 64.
// Pair (ta=i, tb=31-i). Phase A (t<=ta): waves 0,1 on tb rows, waves 2,3 on
// ta rows (ta completes). Transition: w23 store ta output, switch to tb rows.
// Phase B: w01 even remaining tiles, w23 odd (split-KV, same rows), partials
// combined via LDS at the end. Constant 17 iterations.
// Swapped QK: sc = mfma32(K, Q) -> P[kv][q] lane-local per q=lane&31.
// Softmax: fixed shift (bounded scores), lane-local exp/sum, cross-half
// shfl_xor(32) exchange builds PV A-fragments in registers (no P in LDS).
__global__ __launch_bounds__(256) void attn_fwd(const ushort* __restrict__ qkv,
                                                ushort* __restrict__ y) {
  __shared__ __align__(16) ushort LDS[32768];  // 64 KB
  ushort* K0 = LDS;
  ushort* K1 = LDS + 8192;
  ushort* V0 = LDS + 16384;
  ushort* V1 = LDS + 24576;

  const int tid = threadIdx.x;
  const int lane = tid & 63;
  const int w = tid >> 6;
  const int hf = lane >> 5;
  const int lq = lane & 31;
  const int i = blockIdx.x, bh = blockIdx.y;
  const int b = bh >> 4, h = bh & 15, kvh = h >> 2;
  const int ta = i, tb = 31 - i;
  const size_t tokbase = (size_t)b * 2048;
  const bool isW01 = (w < 2);
  const int sub = isW01 ? w : (w - 2);

  // V staging mapping: thread covers kv0..kv0+3 x d0..d0+7
  const int kv0 = (tid & 15) * 4;
  const int d0 = (tid >> 4) * 8;

  union U16 { uint4 u; ushort s[8]; };
  U16 vA[4], vB[4];

  auto LOADV = [&](U16 (&vr)[4], int T) {
#pragma unroll
    for (int l = 0; l < 4; ++l)
      vr[l].u = *(const uint4*)(qkv + (tokbase + (size_t)T * 64 + kv0 + l) * 3072 +
                                2560 + kvh * 128 + d0);
  };
  // Vt[d][kv], kv-chunk(8) swizzled by d&7; 4 consecutive kv -> ushort4 store
  auto WRITEV = [&](ushort* VB, U16 (&vr)[4]) {
#pragma unroll
    for (int j = 0; j < 8; ++j) {
      int row = d0 + j;
      int ad = row * 64 + ((((kv0 >> 3) ^ (row & 7)) << 3) | (kv0 & 7));
      *(ushort4*)&VB[ad] = make_ushort4(vr[0].s[j], vr[1].s[j], vr[2].s[j], vr[3].s[j]);
    }
  };
  // Ks[kv][d as 16 chunks], chunk swizzled by kv&15; linear LDS dest + pre-swizzled src
  auto STAGEK = [&](ushort* KB, int T) {
#pragma unroll
    for (int it = 0; it < 4; ++it) {
      int c = it * 256 + tid;
      int r = c >> 4, a = c & 15;
      int asrc = a ^ (r & 15);
      async16(&KB[c * 8],
              qkv + (tokbase + (size_t)T * 64 + r) * 3072 + 2048 + kvh * 128 + asrc * 8);
    }
  };

  bf16x8 qf[8];
  auto LOADQ = [&](int qrow0) {
#pragma unroll
    for (int kk = 0; kk < 8; ++kk)
      qf[kk] = *(const bf16x8*)(qkv + (tokbase + qrow0 + lq) * 3072 + h * 128 +
                                kk * 16 + hf * 8);
  };

  const f32x16 Z16 = {0.f,0.f,0.f,0.f,0.f,0.f,0.f,0.f,0.f,0.f,0.f,0.f,0.f,0.f,0.f,0.f};
  f32x16 acc[4];
#pragma unroll
  for (int db = 0; db < 4; ++db) acc[db] = Z16;
  float lsum = 0.f;

  // compute one 32q x 64kv tile from LDS K/V, accumulate into acc/lsum
  auto COMPUTE = [&](const ushort* kb, const ushort* vt, bool domask, int kvbase, int qg) {
#pragma unroll
    for (int kvb = 0; kvb < 2; ++kvb) {
      f32x16 sc = Z16;
      __builtin_amdgcn_s_setprio(1);
#pragma unroll
      for (int kk = 0; kk < 8; ++kk) {
        int kv = kvb * 32 + lq;
        int ch = (2 * kk + hf) ^ (kv & 15);
        bf16x8 kf = *(const bf16x8*)&kb[kv * 128 + ch * 8];
        sc = mfma32(kf, qf[kk], sc);   // C[kv][q]: swapped
      }
      __builtin_amdgcn_s_setprio(0);
      if (domask) {
#pragma unroll
        for (int r = 0; r < 16; ++r) {
          int kvl = (r & 3) + 8 * (r >> 2) + 4 * hf;
          if (kvbase + kvb * 32 + kvl > qg) sc[r] = -1.0e30f;
        }
      }
      // cross-half exchange -> PV A fragments (all in registers)
      float ex[16];
#pragma unroll
      for (int r = 0; r < 16; ++r) ex[r] = __shfl_xor(sc[r], 32);
#pragma unroll
      for (int c2 = 0; c2 < 2; ++c2) {
        bf16x8 pa;
#pragma unroll
        for (int j = 0; j < 8; ++j) {
          int r0 = 8 * c2 + (j & 3);
          int r1 = r0 + 4;
          float v0 = (j < 4) ? sc[r0] : ex[r0];   // half 0
          float v1 = (j < 4) ? ex[r1] : sc[r1];   // half 1
          float v = hf ? v1 : v0;
          float p = __builtin_amdgcn_exp2f(fmaf(v, LOG2E, -FIXC));
          lsum += p;
          pa[j] = __builtin_bit_cast(__bf16, f2b(p));
        }
        int kkpv = 2 * kvb + c2;
        __builtin_amdgcn_s_setprio(1);
#pragma unroll
        for (int db = 0; db < 4; ++db) {
          int d = db * 32 + lq;
          int ch = (2 * kkpv + hf) ^ (d & 7);
          bf16x8 vbf = *(const bf16x8*)&vt[d * 64 + ch * 8];
          acc[db] = mfma32(pa, vbf, acc[db]);
        }
        __builtin_amdgcn_s_setprio(0);
      }
    }
  };

  auto STOREO = [&](size_t rowbase, float lf) {
    float rl = 1.0f / lf;
#pragma unroll
    for (int r = 0; r < 16; ++r) {
      int q2 = (r & 3) + 8 * (r >> 2) + 4 * hf;
      float rlq = __shfl(rl, q2);
#pragma unroll
      for (int db = 0; db < 4; ++db) {
        int d = db * 32 + lq;
        y[(rowbase + q2) * 2048 + h * 128 + d] = f2b(acc[db][r] * rlq);
      }
    }
  };

  const int qrowA = (isW01 ? tb : ta) * 64 + sub * 32;
  const int qgA = qrowA + lq;
  LOADQ(qrowA);

  // ---- phase A prologue ----
  LOADV(vA, 0);
  STAGEK(K0, 0);
  WRITEV(V0, vA);
  __syncthreads();

  // ---- phase A: t = 0..ta, all 4 waves ----
  for (int t = 0; t <= ta; ++t) {
    ushort* kb = (t & 1) ? K1 : K0;
    ushort* vb = (t & 1) ? V1 : V0;
    bool more = (t < ta);
    if (more) {
      STAGEK((t & 1) ? K0 : K1, t + 1);
      LOADV(vA, t + 1);
    }
    COMPUTE(kb, vb, (!isW01 && t == ta), t * 64, qgA);
    if (more) WRITEV((t & 1) ? V0 : V1, vA);
    __syncthreads();
  }

  // ---- transition: w23 finalize ta, switch to tb rows ----
  if (!isW01) {
    float lf = lsum + __shfl_xor(lsum, 32);
    STOREO(tokbase + (size_t)ta * 64 + sub * 32, lf);
#pragma unroll
    for (int db = 0; db < 4; ++db) acc[db] = Z16;
    lsum = 0.f;
    LOADQ(tb * 64 + sub * 32);
  }
  const int qgB = tb * 64 + sub * 32 + lq;

  // stage first phase-B pair
  {
    int t0 = ta + 1;
    bool h1 = (t0 + 1 <= tb);
    STAGEK(K0, t0);
    if (h1) STAGEK(K1, t0 + 1);
    LOADV(vA, t0);
    if (h1) LOADV(vB, t0 + 1);
    WRITEV(V0, vA);
    if (h1) WRITEV(V1, vB);
  }
  __syncthreads();

  // ---- phase B: w01 even tiles, w23 odd tiles (split-KV over tb rows) ----
  for (int m = 0;; ++m) {
    int t0 = ta + 1 + 2 * m, t1 = t0 + 1;
    bool has1 = (t1 <= tb);
    bool morePairs = (t0 + 2 <= tb);
    bool more1 = (t0 + 3 <= tb);
    if (morePairs) {
      LOADV(vA, t0 + 2);
      if (more1) LOADV(vB, t0 + 3);
    }
    if (isW01) {
      COMPUTE(K0, V0, (t0 == tb), t0 * 64, qgB);
    } else if (has1) {
      COMPUTE(K1, V1, false, t1 * 64, qgB);
    }
    __syncthreads();
    if (!morePairs) break;
    STAGEK(K0, t0 + 2);
    if (more1) STAGEK(K1, t0 + 3);
    WRITEV(V0, vA);
    if (more1) WRITEV(V1, vB);
    __syncthreads();
  }

  // ---- final epilogue: combine partials (w23 -> LDS scratch -> w01) ----
  float* scf = (float*)LDS;  // 2 x (32q x 128d) f32 + 2 x 64 lsum: 33 KB < 64 KB
  if (!isW01) {
    float lf = lsum + __shfl_xor(lsum, 32);
    int p = sub;
#pragma unroll
    for (int db = 0; db < 4; ++db)
#pragma unroll
      for (int r = 0; r < 16; ++r)
        scf[p * 4096 + (db * 16 + r) * 64 + lane] = acc[db][r];
    scf[8192 + p * 64 + lane] = lf;
  }
  __syncthreads();
  if (isW01) {
    int p = sub;
#pragma unroll
    for (int db = 0; db < 4; ++db)
#pragma unroll
      for (int r = 0; r < 16; ++r)
        acc[db][r] += scf[p * 4096 + (db * 16 + r) * 64 + lane];
    float lf = lsum + __shfl_xor(lsum, 32) + scf[8192 + p * 64 + lane];
    STOREO(tokbase + (size_t)tb * 64 + sub * 32, lf);
  }
}

// ---------------- launcher ----------------
extern "C" void kernel_launch(void* const* d_in, const int* in_sizes, int n_in,
                              void* d_out, int out_size, void* d_ws, size_t ws_size,
                              hipStream_t stream) {
  const float* x  = (const float*)d_in[0];   // 2*2048*2048
  const float* Wq = (const float*)d_in[1];   // 2048*2048
  const float* Wk = (const float*)d_in[2];   // 512*2048
  const float* Wv = (const float*)d_in[3];   // 512*2048
  const float* Wp = (const float*)d_in[4];   // 2048*2048
  const float* qg = (const float*)d_in[5];   // 16
  float* out = (float*)d_out;

  char* w = (char*)d_ws;
  ushort* xb    = (ushort*)w; w += (size_t)4096 * 2048 * 2;
  ushort* wqkv  = (ushort*)w; w += (size_t)3072 * 2048 * 2;
  ushort* wproj = (ushort*)w; w += (size_t)2048 * 2048 * 2;
  ushort* qkv   = (ushort*)w; w += (size_t)4096 * 3072 * 2;
  ushort* yb    = (ushort*)w; w += (size_t)4096 * 2048 * 2;
  float*  cosT  = (float*)w;  w += (size_t)2048 * 64 * 4;
  float*  sinT  = (float*)w;  w += (size_t)2048 * 64 * 4;

  castk<<<8192, 256, 0, stream>>>(x, xb);
  castk<<<4096, 256, 0, stream>>>(Wq, wqkv);
  castk<<<1024, 256, 0, stream>>>(Wk, wqkv + (size_t)2048 * 2048);
  castk<<<1024, 256, 0, stream>>>(Wv, wqkv + (size_t)2560 * 2048);
  castk<<<4096, 256, 0, stream>>>(Wp, wproj);
  rope_tables<<<2048, 64, 0, stream>>>(cosT, sinT);

  // QKV = x * [Wq;Wk;Wv]^T   (M=4096, N=3072, K=2048)
  gemm_bt<ushort><<<dim3(24, 32), 256, 0, stream>>>(xb, wqkv, qkv, 4096, 3072, 2048);
  rms_rope<<<20480, 256, 0, stream>>>(qkv, qg, cosT, sinT);
  // attention -> yb (4096 x 2048): 32x32-mfma swapped-QK flash, paired tiles
  attn_fwd<<<dim3(16, 32), 256, 0, stream>>>(qkv, yb);
  // out = yb * Wproj^T  (M=4096, N=2048, K=2048), f32 out
  gemm_bt<float><<<dim3(16, 32), 256, 0, stream>>>(yb, wproj, out, 4096, 2048, 2048);
}